// Round 1
// baseline (124.324 us; speedup 1.0000x reference)
//
#include <hip/hip_runtime.h>

#define B_IMG 32
#define N_PIX (512 * 512)
#define NB 256            // 16 octaves x 16 sub-bins (4 mantissa bits)
#define REP 8             // histogram replicas to kill LDS atomic same-address serialization
#define SHIFT 19
#define LO_IDX 1840       // (exp_biased=115) << 4  => clamp range 2^-12 .. 2^3
#define BPI 64            // blocks per image
#define CHUNK (N_PIX / BPI)   // 4096 px per block
#define FIXSCALE 1048576.0f   // 2^20 fixed point for packed bin sums
#define MASK40 ((1ull << 40) - 1)

// ---------------- Pass 1: per-block partial histogram (packed u64, 8-way replicated) ----
// Packs per-bin {count, sum} into one u64: [63:40]=count, [39:0]=sum in 2^-20 fixed pt.
// Max per block: cnt<=4096 (24 bits ok), sum<=4096*16*2^20 < 2^37 (40 bits ok).
// Replication: bin bb, replica r=tid&7 lives at s_hist[bb*8+r]; a bin's replicas hit 8
// distinct LDS banks, so intra-wave same-bin atomic pileups drop ~8x.
__global__ __launch_bounds__(256, 4) void hist_kernel(
    const float4* __restrict__ pred, const float4* __restrict__ targ,
    const int4* __restrict__ mask, unsigned long long* __restrict__ g_part,
    double* __restrict__ accs, unsigned* __restrict__ counter) {
  __shared__ unsigned long long s_hist[NB * REP];   // 16 KB
  const int tid = threadIdx.x;
#pragma unroll
  for (int i = tid; i < NB * REP; i += 256) s_hist[i] = 0ull;
  if (tid == 0) {  // zero the K2 accumulators; stream-ordered before K2 runs
    accs[0] = 0.0; accs[1] = 0.0; *counter = 0u;
  }
  __syncthreads();

  const int rep = tid & (REP - 1);
  const int base4 = blockIdx.x * (CHUNK / 4);

#define BIN1(pp, tt, mm)                                                     \
  if ((mm) > 0) {                                                            \
    const float e = fabsf((pp) - (tt));                                      \
    int bb = (int)(__float_as_uint(e) >> SHIFT) - LO_IDX;                    \
    bb = bb < 0 ? 0 : (bb > NB - 1 ? NB - 1 : bb);                           \
    const unsigned long long pkt =                                           \
        (1ull << 40) | (unsigned long long)__float2uint_rn(e * FIXSCALE);    \
    atomicAdd(&s_hist[(bb << 3) | rep], pkt);                                \
  }

  // double-buffered prefetch: batch j+1 loads in flight while binning batch j
  float4 p0 = pred[base4 + tid];
  float4 t0 = targ[base4 + tid];
  int4 m0 = mask[base4 + tid];
#pragma unroll
  for (int j = 0; j < 4; ++j) {
    float4 p1, t1;
    int4 m1;
    if (j < 3) {
      const int idx = base4 + (j + 1) * 256 + tid;
      p1 = pred[idx]; t1 = targ[idx]; m1 = mask[idx];
    }
    BIN1(p0.x, t0.x, m0.x)
    BIN1(p0.y, t0.y, m0.y)
    BIN1(p0.z, t0.z, m0.z)
    BIN1(p0.w, t0.w, m0.w)
    p0 = p1; t0 = t1; m0 = m1;
  }
  __syncthreads();

  // merge replicas (exact integer adds; no carry into count field since sum < 2^36)
  // then flush: plain coalesced store, no atomics, no pre-zero needed
  if (tid < NB) {
    unsigned long long v = 0ull;
#pragma unroll
    for (int r = 0; r < REP; ++r) v += s_hist[(tid << 3) | r];
    g_part[(size_t)blockIdx.x * NB + tid] = v;
  }
}

// ---------------- Pass 2: per-image selection + trimmed sum + final divide ----------------
__global__ __launch_bounds__(256) void finalize_kernel(
    const unsigned long long* __restrict__ g_part, double* __restrict__ accs,
    unsigned* __restrict__ counter, float* __restrict__ out) {
  const int b = blockIdx.x;
  const int tid = threadIdx.x;   // 256 threads, one bin each
  const unsigned long long* base = g_part + (size_t)b * BPI * NB;

  // reduce 64 partials for this image's bin `tid`
  unsigned long long fix = 0ull;
  unsigned c = 0u;
#pragma unroll 8
  for (int p = 0; p < BPI; ++p) {
    const unsigned long long v = base[(size_t)p * NB + tid];
    c += (unsigned)(v >> 40);
    fix += (v & MASK40);
  }
  const double s = (double)fix * (1.0 / (double)FIXSCALE);

  __shared__ unsigned s_scan[NB];
  __shared__ int s_bin;
  __shared__ unsigned s_cbelow;
  __shared__ double s_red[NB];

  s_scan[tid] = c;
  if (tid == 0) { s_bin = 0; s_cbelow = 0; }
  __syncthreads();
  // Hillis-Steele inclusive scan of counts
#pragma unroll
  for (int off = 1; off < NB; off <<= 1) {
    const unsigned add = (tid >= off) ? s_scan[tid - off] : 0u;
    __syncthreads();
    s_scan[tid] += add;
    __syncthreads();
  }
  const unsigned incl = s_scan[tid];
  const unsigned excl = incl - c;
  const unsigned M = s_scan[NB - 1];                      // all valid px land in a bin
  const unsigned k = (unsigned)floorf(0.8f * (float)M);   // matches ref's f32 floor

  if (k > 0 && excl < k && k <= incl) { s_bin = tid; s_cbelow = excl; }
  __syncthreads();

  const int bstar = s_bin;
  double acc = (tid < bstar) ? s : 0.0;   // full bins below boundary: exact sums
  if (tid == bstar && k > 0) {
    const unsigned r = k - s_cbelow;      // 1 <= r <= c
    double part;
    if (r >= c) {
      part = s;                           // exact: whole bin kept
    } else {
      const float lo = __uint_as_float((unsigned)(bstar + LO_IDX) << SHIFT);
      const double mean = s / (double)c;
      double h = mean - (double)lo;
      if (h < 0.0) h = 0.0;
      part = (double)r * (double)lo + ((double)r * (double)r / (double)c) * h;
      if (part > s) part = s;
    }
    acc += part;
  }

  // block reduce doubles
  s_red[tid] = acc;
  __syncthreads();
  for (int st = 128; st > 0; st >>= 1) {
    if (tid < st) s_red[tid] += s_red[tid + st];
    __syncthreads();
  }
  if (tid == 0) {
    atomicAdd(&accs[0], s_red[0]);                     // numerator
    atomicAdd(&accs[1], (double)(0.8f * (float)M));    // divisor term
    __threadfence();
    const unsigned old = atomicAdd(counter, 1u);
    if (old == (unsigned)(B_IMG - 1)) {                // last block finalizes
      __threadfence();
      const double num = atomicAdd(&accs[0], 0.0);
      const double den = atomicAdd(&accs[1], 0.0);
      const double r = (den == 0.0) ? 0.0 : num / fmax(den, 1e-30);
      out[0] = (float)r;
    }
  }
}

extern "C" void kernel_launch(void* const* d_in, const int* in_sizes, int n_in,
                              void* d_out, int out_size, void* d_ws, size_t ws_size,
                              hipStream_t stream) {
  const float4* pred = (const float4*)d_in[0];
  const float4* targ = (const float4*)d_in[1];
  const int4* mask = (const int4*)d_in[2];
  float* out = (float*)d_out;

  char* ws = (char*)d_ws;
  unsigned long long* g_part = (unsigned long long*)ws;            // 2048*256*8 = 4 MB
  double* accs = (double*)(ws + (size_t)B_IMG * BPI * NB * 8);     // 16 B
  unsigned* counter = (unsigned*)(ws + (size_t)B_IMG * BPI * NB * 8 + 16);

  hist_kernel<<<B_IMG * BPI, 256, 0, stream>>>(pred, targ, mask, g_part, accs, counter);
  finalize_kernel<<<B_IMG, 256, 0, stream>>>(g_part, accs, counter, out);
}

// Round 2
// 120.559 us; speedup vs baseline: 1.0312x; 1.0312x over previous
//
#include <hip/hip_runtime.h>

#define B_IMG 32
#define N_PIX (512 * 512)
#define NB 256            // 16 octaves x 16 sub-bins (4 mantissa bits)
#define REP 8             // histogram replicas to kill LDS atomic same-address serialization
#define SHIFT 19
#define LO_IDX 1840       // (exp_biased=115) << 4  => clamp range 2^-12 .. 2^3
#define BPI 32            // blocks per image (was 64): amortize per-block fixed costs
#define CHUNK (N_PIX / BPI)   // 8192 px per block
#define NBATCH (CHUNK / 4 / 256)  // 8 float4-batches per thread
#define FIXSCALE 1048576.0f   // 2^20 fixed point for packed bin sums
#define MASK40 ((1ull << 40) - 1)

// ---------------- Pass 1: per-block partial histogram (packed u64, 8-way replicated) ----
// Packs per-bin {count, sum} into one u64: [63:40]=count, [39:0]=sum in 2^-20 fixed pt.
// Max per block: cnt<=8192 (24 bits ok), sum<=8192*16*2^20 < 2^38 (40 bits ok).
// Replication: bin bb, replica r=tid&7 lives at s_hist[bb*8+r]; a bin's replicas hit 8
// distinct LDS banks, so intra-wave same-bin atomic pileups drop ~8x.
__global__ __launch_bounds__(256, 4) void hist_kernel(
    const float4* __restrict__ pred, const float4* __restrict__ targ,
    const int4* __restrict__ mask, unsigned long long* __restrict__ g_part,
    double* __restrict__ accs, unsigned* __restrict__ counter) {
  __shared__ unsigned long long s_hist[NB * REP];   // 16 KB
  const int tid = threadIdx.x;
#pragma unroll
  for (int i = tid; i < NB * REP; i += 256) s_hist[i] = 0ull;
  if (blockIdx.x == 0 && tid == 0) {  // zero K2 accumulators; stream-ordered before K2
    accs[0] = 0.0; accs[1] = 0.0; *counter = 0u;
  }
  __syncthreads();

  const int rep = tid & (REP - 1);
  const int base4 = blockIdx.x * (CHUNK / 4);

#define BIN1(pp, tt, mm)                                                     \
  if ((mm) > 0) {                                                            \
    const float e = fabsf((pp) - (tt));                                      \
    int bb = (int)(__float_as_uint(e) >> SHIFT) - LO_IDX;                    \
    bb = bb < 0 ? 0 : (bb > NB - 1 ? NB - 1 : bb);                           \
    const unsigned long long pkt =                                           \
        (1ull << 40) | (unsigned long long)__float2uint_rn(e * FIXSCALE);    \
    atomicAdd(&s_hist[(bb << 3) | rep], pkt);                                \
  }

  // double-buffered prefetch: batch j+1 loads in flight while binning batch j
  float4 p0 = pred[base4 + tid];
  float4 t0 = targ[base4 + tid];
  int4 m0 = mask[base4 + tid];
#pragma unroll
  for (int j = 0; j < NBATCH; ++j) {
    float4 p1, t1;
    int4 m1;
    if (j < NBATCH - 1) {
      const int idx = base4 + (j + 1) * 256 + tid;
      p1 = pred[idx]; t1 = targ[idx]; m1 = mask[idx];
    }
    BIN1(p0.x, t0.x, m0.x)
    BIN1(p0.y, t0.y, m0.y)
    BIN1(p0.z, t0.z, m0.z)
    BIN1(p0.w, t0.w, m0.w)
    p0 = p1; t0 = t1; m0 = m1;
  }
  __syncthreads();

  // merge replicas (exact integer adds; no carry into count field since sum < 2^38)
  // then flush: plain coalesced store, no atomics, no pre-zero needed
  if (tid < NB) {
    unsigned long long v = 0ull;
#pragma unroll
    for (int r = 0; r < REP; ++r) v += s_hist[(tid << 3) | r];
    g_part[(size_t)blockIdx.x * NB + tid] = v;
  }
}

// ---------------- Pass 2: per-image selection + trimmed sum + final divide ----------------
__global__ __launch_bounds__(256) void finalize_kernel(
    const unsigned long long* __restrict__ g_part, double* __restrict__ accs,
    unsigned* __restrict__ counter, float* __restrict__ out) {
  const int b = blockIdx.x;
  const int tid = threadIdx.x;   // 256 threads, one bin each
  const unsigned long long* base = g_part + (size_t)b * BPI * NB;

  // reduce 32 partials for this image's bin `tid`
  unsigned long long fix = 0ull;
  unsigned c = 0u;
#pragma unroll 8
  for (int p = 0; p < BPI; ++p) {
    const unsigned long long v = base[(size_t)p * NB + tid];
    c += (unsigned)(v >> 40);
    fix += (v & MASK40);
  }
  const double s = (double)fix * (1.0 / (double)FIXSCALE);

  __shared__ unsigned s_scan[NB];
  __shared__ int s_bin;
  __shared__ unsigned s_cbelow;
  __shared__ double s_red[NB];

  s_scan[tid] = c;
  if (tid == 0) { s_bin = 0; s_cbelow = 0; }
  __syncthreads();
  // Hillis-Steele inclusive scan of counts
#pragma unroll
  for (int off = 1; off < NB; off <<= 1) {
    const unsigned add = (tid >= off) ? s_scan[tid - off] : 0u;
    __syncthreads();
    s_scan[tid] += add;
    __syncthreads();
  }
  const unsigned incl = s_scan[tid];
  const unsigned excl = incl - c;
  const unsigned M = s_scan[NB - 1];                      // all valid px land in a bin
  const unsigned k = (unsigned)floorf(0.8f * (float)M);   // matches ref's f32 floor

  if (k > 0 && excl < k && k <= incl) { s_bin = tid; s_cbelow = excl; }
  __syncthreads();

  const int bstar = s_bin;
  double acc = (tid < bstar) ? s : 0.0;   // full bins below boundary: exact sums
  if (tid == bstar && k > 0) {
    const unsigned r = k - s_cbelow;      // 1 <= r <= c
    double part;
    if (r >= c) {
      part = s;                           // exact: whole bin kept
    } else {
      const float lo = __uint_as_float((unsigned)(bstar + LO_IDX) << SHIFT);
      const double mean = s / (double)c;
      double h = mean - (double)lo;
      if (h < 0.0) h = 0.0;
      part = (double)r * (double)lo + ((double)r * (double)r / (double)c) * h;
      if (part > s) part = s;
    }
    acc += part;
  }

  // block reduce doubles
  s_red[tid] = acc;
  __syncthreads();
  for (int st = 128; st > 0; st >>= 1) {
    if (tid < st) s_red[tid] += s_red[tid + st];
    __syncthreads();
  }
  if (tid == 0) {
    atomicAdd(&accs[0], s_red[0]);                     // numerator
    atomicAdd(&accs[1], (double)(0.8f * (float)M));    // divisor term
    __threadfence();
    const unsigned old = atomicAdd(counter, 1u);
    if (old == (unsigned)(B_IMG - 1)) {                // last block finalizes
      __threadfence();
      const double num = atomicAdd(&accs[0], 0.0);
      const double den = atomicAdd(&accs[1], 0.0);
      const double r = (den == 0.0) ? 0.0 : num / fmax(den, 1e-30);
      out[0] = (float)r;
    }
  }
}

extern "C" void kernel_launch(void* const* d_in, const int* in_sizes, int n_in,
                              void* d_out, int out_size, void* d_ws, size_t ws_size,
                              hipStream_t stream) {
  const float4* pred = (const float4*)d_in[0];
  const float4* targ = (const float4*)d_in[1];
  const int4* mask = (const int4*)d_in[2];
  float* out = (float*)d_out;

  char* ws = (char*)d_ws;
  unsigned long long* g_part = (unsigned long long*)ws;            // 1024*256*8 = 2 MB
  double* accs = (double*)(ws + (size_t)B_IMG * BPI * NB * 8);     // 16 B
  unsigned* counter = (unsigned*)(ws + (size_t)B_IMG * BPI * NB * 8 + 16);

  hist_kernel<<<B_IMG * BPI, 256, 0, stream>>>(pred, targ, mask, g_part, accs, counter);
  finalize_kernel<<<B_IMG, 256, 0, stream>>>(g_part, accs, counter, out);
}